// Round 5
// baseline (280.428 us; speedup 1.0000x reference)
//
#include <hip/hip_runtime.h>
#include <cstdint>
#include <cfloat>

#define BATCH 16
#define NBOX 25200
#define CH 85
#define NCLS 80
#define CAP 512
#define SEGCAP 128   // CAP/4, per-sub-counter capacity (mean occupancy ~59)
#define ACC 32       // max picks per (image,class); P(needed>32) ~ 1e-17
#define MAXDET 300
#define RPB 112      // rows per block: 38,080 B LDS -> 4 blocks/CU
#define CNTPAD 16    // ints per counter slot (64B line); segs 0..3 share one line

typedef unsigned long long u64;

__device__ __forceinline__ u64 shflx64(u64 v, int m) {
    int lo = __shfl_xor((int)(unsigned)(v & 0xffffffffu), m);
    int hi = __shfl_xor((int)(unsigned)(v >> 32), m);
    return ((u64)(unsigned)hi << 32) | (u64)(unsigned)lo;
}

// ---------------- kernel A: staged per-row conf/argmax + bucket by (image,class)
// Writes a packed 32B record per candidate: [float4 offset-box][u64 key][8B pad]
// so nms_kernel never touches p (kills the scattered line-gather there).
__global__ __launch_bounds__(256) void pre_kernel(const float* __restrict__ p,
                                                  int* __restrict__ cnt,
                                                  u64* __restrict__ rec,
                                                  float* __restrict__ outZero,
                                                  int outN) {
#pragma clang fp contract(off)
    __shared__ float s[RPB * CH];          // 38,080 B
    int tid = threadIdx.x;

    // fold hipMemsetAsync(out): first blocks store one zero each-thread
    long z = (long)blockIdx.x * 256 + tid;
    if (z < outN) outZero[z] = 0.0f;

    long blockRow = (long)blockIdx.x * RPB;

    // async global->LDS staging, 16B/lane, lane-contiguous (wave-uniform base + lane*16)
    const float4* p4 = (const float4*)(p + blockRow * CH);
    float4* s4 = (float4*)s;
    for (int t = tid; t < RPB * CH / 4; t += 256) {
        __builtin_amdgcn_global_load_lds(
            (const __attribute__((address_space(1))) void*)(p4 + t),
            (__attribute__((address_space(3))) void*)(s4 + (t & ~63)),
            16, 0, 0);
    }
    __syncthreads();

    int r = tid >> 1;                      // row 0..127 (only <RPB valid)
    int half = tid & 1;                    // classes [0,40) vs [40,80)
    if (r < RPB) {
        const float* row = s + r * CH;
        float obj = row[4];

        float v = -FLT_MAX; int c = 1000;
        int c0 = half * 40;
        for (int k = 0; k < 40; k++) {
            float sc = row[5 + c0 + k] * obj;  // multiply-first, matches reference
            int cc = c0 + k;
            if (sc > v) { v = sc; c = cc; }    // strict > keeps first max
        }
        float v2 = __shfl_xor(v, 1);
        int   cz = __shfl_xor(c, 1);
        if (v2 > v || (v2 == v && cz < c)) { v = v2; c = cz; }

        if (half == 0 && obj > 0.25f && v > 0.25f) {
            int wid = (int)blockRow + r;
            int b   = wid / NBOX;
            int idx = wid - b * NBOX;          // < 25200 < 2^15
            u64 key = ((u64)__float_as_uint(v) << 22) | ((u64)(32767 - idx) << 7) | (u64)c;
            int bkt = b * NCLS + c;
            int seg = idx & 3;
            int pos = atomicAdd(&cnt[bkt * CNTPAD + seg], 1);
            if (pos < SEGCAP) {
                float x = row[0], y = row[1], w = row[2], h = row[3];
                float hw = w * 0.5f, hh = h * 0.5f;
                float offc = (float)c * 4096.0f;
                float4 b4;
                b4.x = (x - hw) + offc; b4.y = (y - hh) + offc;
                b4.z = (x + hw) + offc; b4.w = (y + hh) + offc;
                u64* slot = rec + ((long)bkt * CAP + seg * SEGCAP + pos) * 4;
                *(float4*)slot = b4;       // bytes [0,16): offset box
                slot[2] = key;             // bytes [16,24): key
            }
        }
    }
}

// ---------------- kernel B: sort + EXACT batched greedy NMS --------------------
// Keys tagged with slot (key<<9|slot) ride the lane-major bitonic; boxes wait in
// LDS by slot. Greedy runs in batches of <=8: one 8x8 pairwise-IoU shot (lane =
// i*8+j) -> ballot matrix -> scalar resolve -> one fused suppression pass.
// Picked members are retired EXPLICITLY by owner lane (no reliance on
// self-IoU, which would NaN on a zero-area box). Exactly equivalent to serial
// greedy NMS: batch = prefix of live list; suppressors are always earlier picks.
__global__ __launch_bounds__(64) void nms_kernel(const int* __restrict__ cnt,
                                                 const u64* __restrict__ rec,
                                                 u64* __restrict__ accKey) {
#pragma clang fp contract(off)
    __shared__ float4 posBox[CAP];         // 8,192 B, indexed by slot
    __shared__ u64    posKey[CAP];         // 4,096 B, indexed by slot
    int lane = threadIdx.x;                // one wave per block
    int bkt = blockIdx.x;

    const int* cb = cnt + bkt * CNTPAD;
    int ns[4];
#pragma unroll
    for (int s2 = 0; s2 < 4; s2++) {
        int v = cb[s2];
        ns[s2] = (v < SEGCAP) ? v : SEGCAP;
    }

    // coalesced record load; stage boxes/keys to LDS by slot; build tagged keys
    const u64* R = rec + (long)bkt * CAP * 4;
    u64 key[8];
#pragma unroll
    for (int r = 0; r < 8; r++) {
        int slot = (r << 6) | lane;             // lane-contiguous: conflict-free
        float4 b4 = *(const float4*)(R + (long)slot * 4);
        u64 k = R[(long)slot * 4 + 2];
        posBox[slot] = b4;
        posKey[slot] = k;
        int off = ((r & 1) << 6) | lane;        // offset within segment r>>1
        key[r] = (off < ns[r >> 1]) ? ((k << 9) | (u64)slot) : 0ULL;
    }
    __syncthreads();                            // LDS staging visible wave-wide

    // ---- bitonic sort, descending, lane-major labels: pos = (lane<<3)|r ----
#define CE_XL(K, LM)                                                    \
    { bool d = ((lane & ((K) >> 3)) == 0);                              \
      _Pragma("unroll")                                                 \
      for (int r = 0; r < 8; r++) {                                     \
          u64 part = shflx64(key[r], (LM));                             \
          bool up = ((lane & (LM)) == 0);                               \
          bool gt = key[r] > part;                                      \
          u64 mx = gt ? key[r] : part;                                  \
          u64 mn = gt ? part : key[r];                                  \
          key[r] = (d == up) ? mx : mn; } }
#define CE_RR(K, M)                                                    \
    { _Pragma("unroll")                                                \
      for (int r = 0; r < 8; r++) if (!(r & (M))) {                    \
          int r2 = r | (M);                                            \
          u64 a = key[r], e = key[r2];                                 \
          bool d = ((r & (K)) == 0);                                   \
          u64 hi = (a > e) ? a : e, lo = (a > e) ? e : a;              \
          key[r]  = d ? hi : lo;                                       \
          key[r2] = d ? lo : hi; } }
#define CE_RL(K, M)                                                    \
    { bool d = ((lane & ((K) >> 3)) == 0);                             \
      _Pragma("unroll")                                                \
      for (int r = 0; r < 8; r++) if (!(r & (M))) {                    \
          int r2 = r | (M);                                            \
          u64 a = key[r], e = key[r2];                                 \
          u64 hi = (a > e) ? a : e, lo = (a > e) ? e : a;              \
          key[r]  = d ? hi : lo;                                       \
          key[r2] = d ? lo : hi; } }

    CE_RR(2, 1)
    CE_RR(4, 2) CE_RR(4, 1)
    CE_RL(8, 4) CE_RL(8, 2) CE_RL(8, 1)
    CE_XL(16, 1)  CE_RL(16, 4)  CE_RL(16, 2)  CE_RL(16, 1)
    CE_XL(32, 2)  CE_XL(32, 1)  CE_RL(32, 4)  CE_RL(32, 2)  CE_RL(32, 1)
    CE_XL(64, 4)  CE_XL(64, 2)  CE_XL(64, 1)  CE_RL(64, 4)  CE_RL(64, 2)  CE_RL(64, 1)
    CE_XL(128, 8) CE_XL(128, 4) CE_XL(128, 2) CE_XL(128, 1)
    CE_RL(128, 4) CE_RL(128, 2) CE_RL(128, 1)
    CE_XL(256, 16) CE_XL(256, 8) CE_XL(256, 4) CE_XL(256, 2) CE_XL(256, 1)
    CE_RL(256, 4)  CE_RL(256, 2) CE_RL(256, 1)
    CE_XL(512, 32) CE_XL(512, 16) CE_XL(512, 8) CE_XL(512, 4) CE_XL(512, 2) CE_XL(512, 1)
    CE_RL(512, 4)  CE_RL(512, 2)  CE_RL(512, 1)
#undef CE_XL
#undef CE_RR
#undef CE_RL

    // ---- pull each sorted position's box from LDS (by slot tag) ----
    float x1[8], y1[8], x2[8], y2[8], ar[8];
    unsigned live = 0;
#pragma unroll
    for (int r = 0; r < 8; r++) {
        int slot = (int)(key[r] & 511u);
        float4 B = posBox[slot];
        x1[r] = B.x; y1[r] = B.y; x2[r] = B.z; y2[r] = B.w;
        ar[r] = (B.z - B.x) * (B.w - B.y);
        if (key[r] != 0ULL) live |= 1u << r;
    }

    // ---- batched greedy: resolve <=8 picks per round, exact ----
    long obase = (long)bkt * ACC;
    int nacc = 0;
    u64 lmask = __ballot(live != 0);
    while (lmask != 0ULL && nacc < ACC) {
        // gather next <=8 live positions (ascending pos = (L<<3)|r = descending key)
        u64 bs01 = 0, bs23 = 0;            // 4x16-bit slot fields each
        u64 bp01 = 0, bp23 = 0;            // 4x16-bit pos  fields each
        int bn = 0;
        u64 wm = lmask;
        while (bn < 8 && wm != 0ULL) {
            int L = (int)__ffsll((long long)wm) - 1;
            unsigned lv = (unsigned)__builtin_amdgcn_readlane((int)live, L);
            while (lv && bn < 8) {
                int r0 = __ffs((int)lv) - 1;
                lv &= lv - 1;
                // slot = low 9 bits of key[r0] on lane L
                int klo;
                switch (r0) {
                    case 0: klo = __builtin_amdgcn_readlane((int)(key[0] & 0xffffffffu), L); break;
                    case 1: klo = __builtin_amdgcn_readlane((int)(key[1] & 0xffffffffu), L); break;
                    case 2: klo = __builtin_amdgcn_readlane((int)(key[2] & 0xffffffffu), L); break;
                    case 3: klo = __builtin_amdgcn_readlane((int)(key[3] & 0xffffffffu), L); break;
                    case 4: klo = __builtin_amdgcn_readlane((int)(key[4] & 0xffffffffu), L); break;
                    case 5: klo = __builtin_amdgcn_readlane((int)(key[5] & 0xffffffffu), L); break;
                    case 6: klo = __builtin_amdgcn_readlane((int)(key[6] & 0xffffffffu), L); break;
                    default:klo = __builtin_amdgcn_readlane((int)(key[7] & 0xffffffffu), L); break;
                }
                u64 slot = (u64)(klo & 511);
                u64 posn = (u64)((L << 3) | r0);
                if (bn < 4) { bs01 |= slot << (16 * bn);       bp01 |= posn << (16 * bn); }
                else        { bs23 |= slot << (16 * (bn - 4)); bp23 |= posn << (16 * (bn - 4)); }
                bn++;
            }
            wm &= wm - 1;
        }

        // pairwise suppression matrix: lane = i*8+j computes "pick i suppresses j"
        int pi = lane >> 3, pj = lane & 7;
        u64 wi = (pi < 4) ? bs01 : bs23;
        u64 wj = (pj < 4) ? bs01 : bs23;
        int spi = (int)((wi >> (16 * (pi & 3))) & 0xFFFFu);
        int spj = (int)((wj >> (16 * (pj & 3))) & 0xFFFFu);
        float4 Bi = posBox[spi & 511];
        float4 Bj = posBox[spj & 511];
        float pxx1 = fmaxf(Bi.x, Bj.x), pyy1 = fmaxf(Bi.y, Bj.y);
        float pxx2 = fminf(Bi.z, Bj.z), pyy2 = fminf(Bi.w, Bj.w);
        float pint = fmaxf(pxx2 - pxx1, 0.0f) * fmaxf(pyy2 - pyy1, 0.0f);
        float Ai = (Bi.z - Bi.x) * (Bi.w - Bi.y);
        float Aj = (Bj.z - Bj.x) * (Bj.w - Bj.y);
        float puni = (Ai + Aj) - pint;
        bool supp = (pi < pj) && (pint / puni > 0.45f);
        u64 M = __ballot(supp);

        // scalar greedy resolve within batch (exact serial semantics):
        // member k dies iff some earlier PICKED i has M[i*8+k]
        u64 pickedSpread = 0; unsigned picked8 = 0; int cnt2 = 0;
        int room = ACC - nacc;
        for (int k = 0; k < 8; k++) {
            if (k >= bn || cnt2 >= room) break;
            bool dead = ((M >> k) & pickedSpread) != 0ULL;
            if (!dead) { pickedSpread |= 1ULL << (8 * k); picked8 |= 1u << k; cnt2++; }
        }

        // parallel accKey writes (lanes 0..7), descending order preserved
        if (lane < 8 && ((picked8 >> lane) & 1u)) {
            u64 w = (lane < 4) ? bs01 : bs23;
            int sp = (int)((w >> (16 * (lane & 3))) & 0xFFFFu);
            int rk = __popc(picked8 & ((1u << lane) - 1u));
            accKey[obase + nacc + rk] = posKey[sp & 511];
        }
        nacc += cnt2;

        // explicit retirement of picked members (guaranteed progress, no
        // dependence on self-IoU), then fused suppression by each pick.
#pragma unroll
        for (int k = 0; k < 8; k++) {
            if ((picked8 >> k) & 1u) {
                int pp = (int)(((k < 4 ? bp01 : bp23) >> (16 * (k & 3))) & 0xFFFFu);
                if (lane == (pp >> 3)) live &= ~(1u << (pp & 7));
                int sp = (int)(((k < 4 ? bs01 : bs23) >> (16 * (k & 3))) & 0xFFFFu);
                float4 B = posBox[sp & 511];
                float A = (B.z - B.x) * (B.w - B.y);
#pragma unroll
                for (int r = 0; r < 8; r++) {
                    if ((live >> r) & 1u) {
                        float xx1 = fmaxf(B.x, x1[r]);
                        float yy1 = fmaxf(B.y, y1[r]);
                        float xx2 = fminf(B.z, x2[r]);
                        float yy2 = fminf(B.w, y2[r]);
                        float inter = fmaxf(xx2 - xx1, 0.0f) * fmaxf(yy2 - yy1, 0.0f);
                        float uni = (A + ar[r]) - inter;
                        if (inter / uni > 0.45f) live &= ~(1u << r);
                    }
                }
            }
        }
        lmask = __ballot(live != 0);
    }
    for (int t2 = nacc + lane; t2 < ACC; t2 += 64) accKey[obase + t2] = 0ULL;
}

// ---------------- kernel C: rank-based merge, no sort, no barriers -------------
__global__ __launch_bounds__(256) void merge_kernel(const float* __restrict__ p,
                                                    const u64* __restrict__ accKey,
                                                    float* __restrict__ outRows,
                                                    float* __restrict__ outKeep) {
#pragma clang fp contract(off)
    __shared__ u64 L[NCLS * ACC];          // 20,480 B
    int tid = threadIdx.x;
    int b = blockIdx.y;
    const u64* src = accKey + (long)b * NCLS * ACC;
    for (int t = tid; t < NCLS * ACC; t += 256) L[t] = src[t];
    __syncthreads();

    int g = blockIdx.x * 256 + tid;        // 0..2559
    u64 key = L[g];
    if (key == 0ULL) return;
    int cOwn = g / ACC;
    int rank = g - cOwn * ACC;

    int d = 1;
    for (; d + 3 < NCLS; d += 4) {
        int ca = cOwn + d;     if (ca >= NCLS) ca -= NCLS;
        int cb = cOwn + d + 1; if (cb >= NCLS) cb -= NCLS;
        int cc = cOwn + d + 2; if (cc >= NCLS) cc -= NCLS;
        int cd = cOwn + d + 3; if (cd >= NCLS) cd -= NCLS;
        const u64* LA = L + ca * ACC;
        const u64* LB = L + cb * ACC;
        const u64* LC = L + cc * ACC;
        const u64* LD = L + cd * ACC;
        int na = 0, nb = 0, nc = 0, nd = 0;
#pragma unroll
        for (int s2 = 32; s2; s2 >>= 1) {
            int ta = na + s2, tb = nb + s2, tc = nc + s2, td = nd + s2;
            if (ta <= ACC && LA[ta - 1] > key) na = ta;
            if (tb <= ACC && LB[tb - 1] > key) nb = tb;
            if (tc <= ACC && LC[tc - 1] > key) nc = tc;
            if (td <= ACC && LD[td - 1] > key) nd = td;
        }
        rank += na + nb + nc + nd;
        if (rank >= MAXDET) return;
    }
    for (; d < NCLS; d++) {
        int c2 = cOwn + d; if (c2 >= NCLS) c2 -= NCLS;
        const u64* Lc = L + c2 * ACC;
        int cn = 0;
#pragma unroll
        for (int s2 = 32; s2; s2 >>= 1) {
            int ncx = cn + s2;
            if (ncx <= ACC && Lc[ncx - 1] > key) cn = ncx;
        }
        rank += cn;
        if (rank >= MAXDET) return;
    }

    int cc  = (int)(key & 127);
    int idx = 32767 - (int)((key >> 7) & 32767);
    float conf = __uint_as_float((unsigned)(key >> 22));
    const float* q = p + ((long)b * NBOX + idx) * CH;
    float x = q[0], y = q[1], w = q[2], h = q[3];
    float hw = w * 0.5f, hh = h * 0.5f;
    float* row = outRows + ((long)b * MAXDET + rank) * 6;
    row[0] = x - hw; row[1] = y - hh; row[2] = x + hw; row[3] = y + hh;
    row[4] = conf;   row[5] = (float)cc;
    outKeep[b * MAXDET + rank] = 1.0f;
}

extern "C" void kernel_launch(void* const* d_in, const int* in_sizes, int n_in,
                              void* d_out, int out_size, void* d_ws, size_t ws_size,
                              hipStream_t stream) {
    const float* p = (const float*)d_in[0];
    float* out = (float*)d_out;

    char* ws = (char*)d_ws;
    int* cnt = (int*)ws;                                    // 81,920 B padded counters
    u64* rec = (u64*)(ws + BATCH * NCLS * CNTPAD * 4);      // 16*80*512*32 B = 20.97 MB
    u64* accKey = (u64*)(ws + BATCH * NCLS * CNTPAD * 4
                            + (size_t)BATCH * NCLS * CAP * 32);  // 327,680 B

    hipMemsetAsync(cnt, 0, BATCH * NCLS * CNTPAD * sizeof(int), stream);
    // out zeroing folded into pre_kernel
    pre_kernel<<<(BATCH * NBOX) / RPB, 256, 0, stream>>>(p, cnt, rec, out, out_size);
    nms_kernel<<<BATCH * NCLS, 64, 0, stream>>>(cnt, rec, accKey);
    dim3 gM(NCLS * ACC / 256, BATCH);
    merge_kernel<<<gM, 256, 0, stream>>>(p, accKey, out, out + (size_t)BATCH * MAXDET * 6);
}

// Round 6
// 278.942 us; speedup vs baseline: 1.0053x; 1.0053x over previous
//
#include <hip/hip_runtime.h>
#include <cstdint>
#include <cfloat>

#define BATCH 16
#define NBOX 25200
#define CH 85
#define NCLS 80
#define CAP 512
#define SEGCAP 128   // CAP/4, per-sub-counter capacity (mean occupancy ~59)
#define ACC 32       // max picks per (image,class); P(needed>32) ~ 1e-17
#define MAXDET 300
#define RPB 112      // rows per block: 38,080 B LDS -> 4 blocks/CU
#define CNTPAD 16    // ints per counter slot (64B line); segs 0..3 share one line

typedef unsigned long long u64;

__device__ __forceinline__ u64 shflx64(u64 v, int m) {
    int lo = __shfl_xor((int)(unsigned)(v & 0xffffffffu), m);
    int hi = __shfl_xor((int)(unsigned)(v >> 32), m);
    return ((u64)(unsigned)hi << 32) | (u64)(unsigned)lo;
}

// ---------------- kernel A: staged per-row conf/argmax + bucket by (image,class)
// Writes a packed 32B record per candidate: [float4 offset-box][u64 key][8B pad]
// so nms_kernel never touches p (kills the latency-bound scattered gather).
__global__ __launch_bounds__(256) void pre_kernel(const float* __restrict__ p,
                                                  int* __restrict__ cnt,
                                                  u64* __restrict__ rec,
                                                  float* __restrict__ outZero,
                                                  int outN) {
#pragma clang fp contract(off)
    __shared__ float s[RPB * CH];          // 38,080 B
    int tid = threadIdx.x;

    // fold hipMemsetAsync(out): first blocks store one zero each-thread
    long z = (long)blockIdx.x * 256 + tid;
    if (z < outN) outZero[z] = 0.0f;

    long blockRow = (long)blockIdx.x * RPB;

    // async global->LDS staging, 16B/lane, lane-contiguous (wave-uniform base + lane*16)
    const float4* p4 = (const float4*)(p + blockRow * CH);
    float4* s4 = (float4*)s;
    for (int t = tid; t < RPB * CH / 4; t += 256) {
        __builtin_amdgcn_global_load_lds(
            (const __attribute__((address_space(1))) void*)(p4 + t),
            (__attribute__((address_space(3))) void*)(s4 + (t & ~63)),
            16, 0, 0);
    }
    __syncthreads();

    int r = tid >> 1;                      // row 0..127 (only <RPB valid)
    int half = tid & 1;                    // classes [0,40) vs [40,80)
    if (r < RPB) {
        const float* row = s + r * CH;
        float obj = row[4];

        float v = -FLT_MAX; int c = 1000;
        int c0 = half * 40;
        for (int k = 0; k < 40; k++) {
            float sc = row[5 + c0 + k] * obj;  // multiply-first, matches reference
            int cc = c0 + k;
            if (sc > v) { v = sc; c = cc; }    // strict > keeps first max
        }
        float v2 = __shfl_xor(v, 1);
        int   cz = __shfl_xor(c, 1);
        if (v2 > v || (v2 == v && cz < c)) { v = v2; c = cz; }

        if (half == 0 && obj > 0.25f && v > 0.25f) {
            int wid = (int)blockRow + r;
            int b   = wid / NBOX;
            int idx = wid - b * NBOX;          // < 25200 < 2^15
            u64 key = ((u64)__float_as_uint(v) << 22) | ((u64)(32767 - idx) << 7) | (u64)c;
            int bkt = b * NCLS + c;
            int seg = idx & 3;
            int pos = atomicAdd(&cnt[bkt * CNTPAD + seg], 1);
            if (pos < SEGCAP) {
                float x = row[0], y = row[1], w = row[2], h = row[3];
                float hw = w * 0.5f, hh = h * 0.5f;
                float offc = (float)c * 4096.0f;
                float4 b4;
                b4.x = (x - hw) + offc; b4.y = (y - hh) + offc;
                b4.z = (x + hw) + offc; b4.w = (y + hh) + offc;
                u64* slot = rec + ((long)bkt * CAP + seg * SEGCAP + pos) * 4;
                *(float4*)slot = b4;       // bytes [0,16): offset box
                slot[2] = key;             // bytes [16,24): key
            }
        }
    }
}

// ---------------- kernel B: record load + tagged sort + cursor greedy ---------
// R3's proven cursor pick loop, fed by pre's records instead of a scattered
// global gather. Keys tagged with slot (key<<9|slot) ride the lane-major
// bitonic; after the sort, LDS is rewritten in sorted-position order so the
// cursor's broadcast read is a single uniform ds_read_b128.
__global__ __launch_bounds__(64) void nms_kernel(const int* __restrict__ cnt,
                                                 const u64* __restrict__ rec,
                                                 u64* __restrict__ accKey) {
#pragma clang fp contract(off)
    __shared__ float4 posBox[CAP];         // 8,192 B: slot-indexed, then sorted-pos
    __shared__ u64    posKeyS[CAP];        // 4,096 B: sorted-pos untagged keys
    int lane = threadIdx.x;                // one wave per block
    int bkt = blockIdx.x;

    const int* cb = cnt + bkt * CNTPAD;
    int ns[4];
#pragma unroll
    for (int s2 = 0; s2 < 4; s2++) {
        int v = cb[s2];
        ns[s2] = (v < SEGCAP) ? v : SEGCAP;
    }

    // 1) coalesced record load -> posBox[slot] staged, keys tagged in regs
    const u64* R = rec + (long)bkt * CAP * 4;
    u64 key[8];
#pragma unroll
    for (int r = 0; r < 8; r++) {
        int slot = (r << 6) | lane;             // lane-contiguous: conflict-free
        float4 b4 = *(const float4*)(R + (long)slot * 4);
        u64 k = R[(long)slot * 4 + 2];
        posBox[slot] = b4;
        int off = ((r & 1) << 6) | lane;        // offset within segment r>>1
        key[r] = (off < ns[r >> 1]) ? ((k << 9) | (u64)slot) : 0ULL;
    }
    __syncthreads();

    // 2) bitonic sort, descending, lane-major labels: pos = (lane<<3)|r
#define CE_XL(K, LM)                                                    \
    { bool d = ((lane & ((K) >> 3)) == 0);                              \
      _Pragma("unroll")                                                 \
      for (int r = 0; r < 8; r++) {                                     \
          u64 part = shflx64(key[r], (LM));                             \
          bool up = ((lane & (LM)) == 0);                               \
          bool gt = key[r] > part;                                      \
          u64 mx = gt ? key[r] : part;                                  \
          u64 mn = gt ? part : key[r];                                  \
          key[r] = (d == up) ? mx : mn; } }
#define CE_RR(K, M)                                                    \
    { _Pragma("unroll")                                                \
      for (int r = 0; r < 8; r++) if (!(r & (M))) {                    \
          int r2 = r | (M);                                            \
          u64 a = key[r], e = key[r2];                                 \
          bool d = ((r & (K)) == 0);                                   \
          u64 hi = (a > e) ? a : e, lo = (a > e) ? e : a;              \
          key[r]  = d ? hi : lo;                                       \
          key[r2] = d ? lo : hi; } }
#define CE_RL(K, M)                                                    \
    { bool d = ((lane & ((K) >> 3)) == 0);                             \
      _Pragma("unroll")                                                \
      for (int r = 0; r < 8; r++) if (!(r & (M))) {                    \
          int r2 = r | (M);                                            \
          u64 a = key[r], e = key[r2];                                 \
          u64 hi = (a > e) ? a : e, lo = (a > e) ? e : a;              \
          key[r]  = d ? hi : lo;                                       \
          key[r2] = d ? lo : hi; } }

    CE_RR(2, 1)
    CE_RR(4, 2) CE_RR(4, 1)
    CE_RL(8, 4) CE_RL(8, 2) CE_RL(8, 1)
    CE_XL(16, 1)  CE_RL(16, 4)  CE_RL(16, 2)  CE_RL(16, 1)
    CE_XL(32, 2)  CE_XL(32, 1)  CE_RL(32, 4)  CE_RL(32, 2)  CE_RL(32, 1)
    CE_XL(64, 4)  CE_XL(64, 2)  CE_XL(64, 1)  CE_RL(64, 4)  CE_RL(64, 2)  CE_RL(64, 1)
    CE_XL(128, 8) CE_XL(128, 4) CE_XL(128, 2) CE_XL(128, 1)
    CE_RL(128, 4) CE_RL(128, 2) CE_RL(128, 1)
    CE_XL(256, 16) CE_XL(256, 8) CE_XL(256, 4) CE_XL(256, 2) CE_XL(256, 1)
    CE_RL(256, 4)  CE_RL(256, 2) CE_RL(256, 1)
    CE_XL(512, 32) CE_XL(512, 16) CE_XL(512, 8) CE_XL(512, 4) CE_XL(512, 2) CE_XL(512, 1)
    CE_RL(512, 4)  CE_RL(512, 2)  CE_RL(512, 1)
#undef CE_XL
#undef CE_RR
#undef CE_RL

    // 3) register pull: sorted position (r<<6)|lane takes its box via slot tag
    float x1[8], y1[8], x2[8], y2[8], ar[8];
    unsigned live = 0;
#pragma unroll
    for (int r = 0; r < 8; r++) {
        int slot = (int)(key[r] & 511u);
        float4 B = posBox[slot];           // scattered LDS read (one-time)
        x1[r] = B.x; y1[r] = B.y; x2[r] = B.z; y2[r] = B.w;
        ar[r] = (B.z - B.x) * (B.w - B.y);
        if (key[r] != 0ULL) live |= 1u << r;
    }
    __syncthreads();                       // all pulls done before overwrite

    // 4) overwrite LDS in sorted-position order (conflict-free writes)
#pragma unroll
    for (int r = 0; r < 8; r++) {
        int t = (r << 6) | lane;
        posBox[t]  = make_float4(x1[r], y1[r], x2[r], y2[r]);
        posKeyS[t] = key[r] >> 9;          // untagged key (0 for dead)
    }
    __syncthreads();

    // 5) cursor greedy: next pick = first live pos -> one ballot + one
    //    readlane + one uniform ds_read broadcast per pick (R3's loop)
    long obase = (long)bkt * ACC;
    int nacc = 0;
    u64 mask = __ballot(live != 0);
    while (mask != 0ULL) {
        int L = (int)__ffsll((long long)mask) - 1;                 // scalar
        unsigned lv = (unsigned)__builtin_amdgcn_readlane((int)live, L);
        int r0 = __ffs((int)lv) - 1;                               // scalar
        int tp = (r0 << 6) | L;
        float4 B = posBox[tp];             // uniform addr -> LDS broadcast
        u64 kk = posKeyS[tp];
        if (lane == 0) accKey[obase + nacc] = kk;
        nacc++;
        if (lane == L) live &= ~(1u << r0);
        if (nacc == ACC) break;
        float A = (B.z - B.x) * (B.w - B.y);
#pragma unroll
        for (int r = 0; r < 8; r++) {
            if ((live >> r) & 1) {
                float xx1 = fmaxf(B.x, x1[r]);
                float yy1 = fmaxf(B.y, y1[r]);
                float xx2 = fminf(B.z, x2[r]);
                float yy2 = fminf(B.w, y2[r]);
                float inter = fmaxf(xx2 - xx1, 0.0f) * fmaxf(yy2 - yy1, 0.0f);
                float uni = (A + ar[r]) - inter;
                if (inter / uni > 0.45f) live &= ~(1u << r);
            }
        }
        mask = __ballot(live != 0);
    }
    for (int t2 = nacc + lane; t2 < ACC; t2 += 64) accKey[obase + t2] = 0ULL;
}

// ---------------- kernel C: rank-based merge, no sort, no barriers -------------
__global__ __launch_bounds__(256) void merge_kernel(const float* __restrict__ p,
                                                    const u64* __restrict__ accKey,
                                                    float* __restrict__ outRows,
                                                    float* __restrict__ outKeep) {
#pragma clang fp contract(off)
    __shared__ u64 L[NCLS * ACC];          // 20,480 B
    int tid = threadIdx.x;
    int b = blockIdx.y;
    const u64* src = accKey + (long)b * NCLS * ACC;
    for (int t = tid; t < NCLS * ACC; t += 256) L[t] = src[t];
    __syncthreads();

    int g = blockIdx.x * 256 + tid;        // 0..2559
    u64 key = L[g];
    if (key == 0ULL) return;
    int cOwn = g / ACC;
    int rank = g - cOwn * ACC;

    int d = 1;
    for (; d + 3 < NCLS; d += 4) {
        int ca = cOwn + d;     if (ca >= NCLS) ca -= NCLS;
        int cb = cOwn + d + 1; if (cb >= NCLS) cb -= NCLS;
        int cc = cOwn + d + 2; if (cc >= NCLS) cc -= NCLS;
        int cd = cOwn + d + 3; if (cd >= NCLS) cd -= NCLS;
        const u64* LA = L + ca * ACC;
        const u64* LB = L + cb * ACC;
        const u64* LC = L + cc * ACC;
        const u64* LD = L + cd * ACC;
        int na = 0, nb = 0, nc = 0, nd = 0;
#pragma unroll
        for (int s2 = 32; s2; s2 >>= 1) {
            int ta = na + s2, tb = nb + s2, tc = nc + s2, td = nd + s2;
            if (ta <= ACC && LA[ta - 1] > key) na = ta;
            if (tb <= ACC && LB[tb - 1] > key) nb = tb;
            if (tc <= ACC && LC[tc - 1] > key) nc = tc;
            if (td <= ACC && LD[td - 1] > key) nd = td;
        }
        rank += na + nb + nc + nd;
        if (rank >= MAXDET) return;
    }
    for (; d < NCLS; d++) {
        int c2 = cOwn + d; if (c2 >= NCLS) c2 -= NCLS;
        const u64* Lc = L + c2 * ACC;
        int cn = 0;
#pragma unroll
        for (int s2 = 32; s2; s2 >>= 1) {
            int ncx = cn + s2;
            if (ncx <= ACC && Lc[ncx - 1] > key) cn = ncx;
        }
        rank += cn;
        if (rank >= MAXDET) return;
    }

    int cc  = (int)(key & 127);
    int idx = 32767 - (int)((key >> 7) & 32767);
    float conf = __uint_as_float((unsigned)(key >> 22));
    const float* q = p + ((long)b * NBOX + idx) * CH;
    float x = q[0], y = q[1], w = q[2], h = q[3];
    float hw = w * 0.5f, hh = h * 0.5f;
    float* row = outRows + ((long)b * MAXDET + rank) * 6;
    row[0] = x - hw; row[1] = y - hh; row[2] = x + hw; row[3] = y + hh;
    row[4] = conf;   row[5] = (float)cc;
    outKeep[b * MAXDET + rank] = 1.0f;
}

extern "C" void kernel_launch(void* const* d_in, const int* in_sizes, int n_in,
                              void* d_out, int out_size, void* d_ws, size_t ws_size,
                              hipStream_t stream) {
    const float* p = (const float*)d_in[0];
    float* out = (float*)d_out;

    char* ws = (char*)d_ws;
    int* cnt = (int*)ws;                                    // 81,920 B padded counters
    u64* rec = (u64*)(ws + BATCH * NCLS * CNTPAD * 4);      // 16*80*512*32 B = 20.97 MB
    u64* accKey = (u64*)(ws + BATCH * NCLS * CNTPAD * 4
                            + (size_t)BATCH * NCLS * CAP * 32);  // 327,680 B

    hipMemsetAsync(cnt, 0, BATCH * NCLS * CNTPAD * sizeof(int), stream);
    // out zeroing folded into pre_kernel
    pre_kernel<<<(BATCH * NBOX) / RPB, 256, 0, stream>>>(p, cnt, rec, out, out_size);
    nms_kernel<<<BATCH * NCLS, 64, 0, stream>>>(cnt, rec, accKey);
    dim3 gM(NCLS * ACC / 256, BATCH);
    merge_kernel<<<gM, 256, 0, stream>>>(p, accKey, out, out + (size_t)BATCH * MAXDET * 6);
}

// Round 9
// 262.814 us; speedup vs baseline: 1.0670x; 1.0614x over previous
//
#include <hip/hip_runtime.h>
#include <cstdint>
#include <cfloat>

#define BATCH 16
#define NBOX 25200
#define CH 85
#define NCLS 80
#define CAP 512
#define SEGCAP 128   // CAP/4, per-sub-counter capacity
#define ACC 32       // max picks per (image,class); P(needed>32) ~ 1e-17
#define MAXDET 300
#define RPB 112      // rows per block: 38,080 B LDS -> 4 blocks/CU
#define CNTPAD 16    // ints per counter slot (64B line); segs 0..3 share one line

typedef unsigned long long u64;

__device__ __forceinline__ u64 shflx64(u64 v, int m) {
    int lo = __shfl_xor((int)(unsigned)(v & 0xffffffffu), m);
    int hi = __shfl_xor((int)(unsigned)(v >> 32), m);
    return ((u64)(unsigned)hi << 32) | (u64)(unsigned)lo;
}

// ---------------- kernel A: staged per-row conf/argmax + bucket by (image,class)
// Writes a packed 32B record per candidate: [float4 offset-box][u64 key][8B pad]
// (unchanged from R6 — verified passing)
__global__ __launch_bounds__(256) void pre_kernel(const float* __restrict__ p,
                                                  int* __restrict__ cnt,
                                                  u64* __restrict__ rec,
                                                  float* __restrict__ outZero,
                                                  int outN) {
#pragma clang fp contract(off)
    __shared__ float s[RPB * CH];          // 38,080 B
    int tid = threadIdx.x;

    long z = (long)blockIdx.x * 256 + tid;
    if (z < outN) outZero[z] = 0.0f;

    long blockRow = (long)blockIdx.x * RPB;

    const float4* p4 = (const float4*)(p + blockRow * CH);
    float4* s4 = (float4*)s;
    for (int t = tid; t < RPB * CH / 4; t += 256) {
        __builtin_amdgcn_global_load_lds(
            (const __attribute__((address_space(1))) void*)(p4 + t),
            (__attribute__((address_space(3))) void*)(s4 + (t & ~63)),
            16, 0, 0);
    }
    __syncthreads();

    int r = tid >> 1;
    int half = tid & 1;
    if (r < RPB) {
        const float* row = s + r * CH;
        float obj = row[4];

        float v = -FLT_MAX; int c = 1000;
        int c0 = half * 40;
        for (int k = 0; k < 40; k++) {
            float sc = row[5 + c0 + k] * obj;  // multiply-first, matches reference
            int cc = c0 + k;
            if (sc > v) { v = sc; c = cc; }    // strict > keeps first max
        }
        float v2 = __shfl_xor(v, 1);
        int   cz = __shfl_xor(c, 1);
        if (v2 > v || (v2 == v && cz < c)) { v = v2; c = cz; }

        if (half == 0 && obj > 0.25f && v > 0.25f) {
            int wid = (int)blockRow + r;
            int b   = wid / NBOX;
            int idx = wid - b * NBOX;
            u64 key = ((u64)__float_as_uint(v) << 22) | ((u64)(32767 - idx) << 7) | (u64)c;
            int bkt = b * NCLS + c;
            int seg = idx & 3;
            int pos = atomicAdd(&cnt[bkt * CNTPAD + seg], 1);
            if (pos < SEGCAP) {
                float x = row[0], y = row[1], w = row[2], h = row[3];
                float hw = w * 0.5f, hh = h * 0.5f;
                float offc = (float)c * 4096.0f;
                float4 b4;
                b4.x = (x - hw) + offc; b4.y = (y - hh) + offc;
                b4.z = (x + hw) + offc; b4.w = (y + hh) + offc;
                u64* slot = rec + ((long)bkt * CAP + seg * SEGCAP + pos) * 4;
                *(float4*)slot = b4;
                slot[2] = key;
            }
        }
    }
}

// ---------------- kernel B: sort + row-matrix greedy NMS (exact) ---------------
// BUG FIX vs R7/R8: the bitonic network sorts by label pos=(lane<<3)|r
// (lane-major). The LDS rewrite must store at THAT index, so posBox[rank] is
// truly the rank-th largest key. R7/R8 stored at (r<<6)|lane, making "tile 0"
// ranks {0,8,16,...} -> deterministic wrong picks (absmax 696 both rounds).
// Per 64-rank tile: lane i builds its kill row (bit j = IoU(i,j)>thr) via 63
// independent pipelined LDS reads; resolve = scalar ffs loop applying one
// uniform-broadcast rowLds read per pick. Exact serial-greedy semantics.
__global__ __launch_bounds__(64) void nms_kernel(const int* __restrict__ cnt,
                                                 const u64* __restrict__ rec,
                                                 u64* __restrict__ accKey) {
#pragma clang fp contract(off)
    __shared__ float4 posBox[CAP];         // 8,192 B: slot-indexed, then RANK-indexed
    __shared__ u64    posKeyS[CAP];        // 4,096 B: rank-indexed untagged keys
    __shared__ u64    rowLds[64];          //   512 B: per-tile kill rows
    __shared__ int    pickPosLds[ACC];     //   128 B: pick ranks (cross-tile)
    int lane = threadIdx.x;                // one wave per block
    int bkt = blockIdx.x;

    const int* cb = cnt + bkt * CNTPAD;
    int ns0 = cb[0], ns1 = cb[1], ns2 = cb[2], ns3 = cb[3];
    ns0 = ns0 < SEGCAP ? ns0 : SEGCAP;
    ns1 = ns1 < SEGCAP ? ns1 : SEGCAP;
    ns2 = ns2 < SEGCAP ? ns2 : SEGCAP;
    ns3 = ns3 < SEGCAP ? ns3 : SEGCAP;
    int nsg[4] = {ns0, ns1, ns2, ns3};
    int ntot = ns0 + ns1 + ns2 + ns3;

    // 1) coalesced record load -> posBox[slot]; tagged keys in regs
    const u64* R = rec + (long)bkt * CAP * 4;
    u64 key[8];
#pragma unroll
    for (int r = 0; r < 8; r++) {
        int slot = (r << 6) | lane;
        float4 b4 = *(const float4*)(R + (long)slot * 4);
        u64 k = R[(long)slot * 4 + 2];
        posBox[slot] = b4;
        int off = ((r & 1) << 6) | lane;        // offset within segment r>>1
        key[r] = (off < nsg[r >> 1]) ? ((k << 9) | (u64)slot) : 0ULL;
    }
    __syncthreads();

    // 2) bitonic sort, descending, lane-major labels: pos = (lane<<3)|r
#define CE_XL(K, LM)                                                    \
    { bool d = ((lane & ((K) >> 3)) == 0);                              \
      _Pragma("unroll")                                                 \
      for (int r = 0; r < 8; r++) {                                     \
          u64 part = shflx64(key[r], (LM));                             \
          bool up = ((lane & (LM)) == 0);                               \
          bool gt = key[r] > part;                                      \
          u64 mx = gt ? key[r] : part;                                  \
          u64 mn = gt ? part : key[r];                                  \
          key[r] = (d == up) ? mx : mn; } }
#define CE_RR(K, M)                                                    \
    { _Pragma("unroll")                                                \
      for (int r = 0; r < 8; r++) if (!(r & (M))) {                    \
          int r2 = r | (M);                                            \
          u64 a = key[r], e = key[r2];                                 \
          bool d = ((r & (K)) == 0);                                   \
          u64 hi = (a > e) ? a : e, lo = (a > e) ? e : a;              \
          key[r]  = d ? hi : lo;                                       \
          key[r2] = d ? lo : hi; } }
#define CE_RL(K, M)                                                    \
    { bool d = ((lane & ((K) >> 3)) == 0);                             \
      _Pragma("unroll")                                                \
      for (int r = 0; r < 8; r++) if (!(r & (M))) {                    \
          int r2 = r | (M);                                            \
          u64 a = key[r], e = key[r2];                                 \
          u64 hi = (a > e) ? a : e, lo = (a > e) ? e : a;              \
          key[r]  = d ? hi : lo;                                       \
          key[r2] = d ? lo : hi; } }

    CE_RR(2, 1)
    CE_RR(4, 2) CE_RR(4, 1)
    CE_RL(8, 4) CE_RL(8, 2) CE_RL(8, 1)
    CE_XL(16, 1)  CE_RL(16, 4)  CE_RL(16, 2)  CE_RL(16, 1)
    CE_XL(32, 2)  CE_XL(32, 1)  CE_RL(32, 4)  CE_RL(32, 2)  CE_RL(32, 1)
    CE_XL(64, 4)  CE_XL(64, 2)  CE_XL(64, 1)  CE_RL(64, 4)  CE_RL(64, 2)  CE_RL(64, 1)
    CE_XL(128, 8) CE_XL(128, 4) CE_XL(128, 2) CE_XL(128, 1)
    CE_RL(128, 4) CE_RL(128, 2) CE_RL(128, 1)
    CE_XL(256, 16) CE_XL(256, 8) CE_XL(256, 4) CE_XL(256, 2) CE_XL(256, 1)
    CE_RL(256, 4)  CE_RL(256, 2) CE_RL(256, 1)
    CE_XL(512, 32) CE_XL(512, 16) CE_XL(512, 8) CE_XL(512, 4) CE_XL(512, 2) CE_XL(512, 1)
    CE_RL(512, 4)  CE_RL(512, 2)  CE_RL(512, 1)
#undef CE_XL
#undef CE_RR
#undef CE_RL

    // 3) pull boxes/keys via slot tag; 4) rewrite LDS in SORT-LABEL (rank) order:
    //    rank of key[r] on this lane is (lane<<3)|r  <-- THE FIX
    float4 pb[8]; u64 pk[8];
#pragma unroll
    for (int r = 0; r < 8; r++) {
        int slot = (int)(key[r] & 511u);
        pb[r] = posBox[slot];
        pk[r] = key[r] >> 9;               // untagged key (0 for dead)
    }
    __syncthreads();
#pragma unroll
    for (int r = 0; r < 8; r++) {
        int t = (lane << 3) | r;           // rank index (was (r<<6)|lane: BUG)
        posBox[t]  = pb[r];
        posKeyS[t] = pk[r];
    }
    __syncthreads();

    // 5) tile loop over ranks: row-matrix build + scalar resolve
    long obase = (long)bkt * ACC;
    int nacc = 0;
    for (int tb = 0; tb < CAP; tb += 64) {
        if (tb >= ntot || nacc >= ACC) break;
        if (tb > 0) __syncthreads();       // pickPosLds/rowLds reuse safe

        bool valid = (tb + lane) < ntot;
        float4 my = posBox[tb + lane];     // rank tb+lane
        float myA = (my.z - my.x) * (my.w - my.y);
        bool dead = !valid;

        // cross-suppression by picks from earlier tiles (rarely reached)
        if (tb > 0) {
            for (int k = 0; k < nacc; k++) {
                float4 B = posBox[pickPosLds[k]];     // uniform, pipelined
                float xx1 = fmaxf(B.x, my.x);
                float yy1 = fmaxf(B.y, my.y);
                float xx2 = fminf(B.z, my.z);
                float yy2 = fminf(B.w, my.w);
                float inter = fmaxf(xx2 - xx1, 0.0f) * fmaxf(yy2 - yy1, 0.0f);
                float A = (B.z - B.x) * (B.w - B.y);
                float uni = (A + myA) - inter;
                if (valid && (inter / uni > 0.45f)) dead = true;
            }
        }

        // kill-row build: bit j = "I suppress rank tb+j" (IoU > thr).
        // 63 INDEPENDENT LDS reads (rotating offset), fully pipelined.
        u64 row = 0;
#pragma unroll 4
        for (int k = 1; k < 64; k++) {
            int j = (lane + k) & 63;
            float4 B = posBox[tb + j];
            float xx1 = fmaxf(my.x, B.x);
            float yy1 = fmaxf(my.y, B.y);
            float xx2 = fminf(my.z, B.z);
            float yy2 = fminf(my.w, B.w);
            float inter = fmaxf(xx2 - xx1, 0.0f) * fmaxf(yy2 - yy1, 0.0f);
            float aj = (B.z - B.x) * (B.w - B.y);
            float uni = (myA + aj) - inter;
            if (inter / uni > 0.45f) row |= 1ULL << j;
        }
        // bits at dead/invalid j are harmless (those j are never alive).

        u64 alive = __ballot(!dead);
        rowLds[lane] = row;
        __syncthreads();                   // rows visible before resolve

        // scalar resolve: exact serial greedy within the tile
        while (alive != 0ULL && nacc < ACC) {
            int pos = (int)__ffsll((long long)alive) - 1;   // lowest rank alive
            if (lane == 0) {
                accKey[obase + nacc] = posKeyS[tb + pos];
                pickPosLds[nacc] = tb + pos;
            }
            nacc++;
            u64 krow = rowLds[pos];        // uniform broadcast ds_read_b64
            alive &= ~krow;
            alive &= ~(1ULL << pos);
        }
    }

    for (int t2 = nacc + lane; t2 < ACC; t2 += 64) accKey[obase + t2] = 0ULL;
}

// ---------------- kernel C: rank-based merge (unchanged, verified) -------------
__global__ __launch_bounds__(256) void merge_kernel(const float* __restrict__ p,
                                                    const u64* __restrict__ accKey,
                                                    float* __restrict__ outRows,
                                                    float* __restrict__ outKeep) {
#pragma clang fp contract(off)
    __shared__ u64 L[NCLS * ACC];          // 20,480 B
    int tid = threadIdx.x;
    int b = blockIdx.y;
    const u64* src = accKey + (long)b * NCLS * ACC;
    for (int t = tid; t < NCLS * ACC; t += 256) L[t] = src[t];
    __syncthreads();

    int g = blockIdx.x * 256 + tid;
    u64 key = L[g];
    if (key == 0ULL) return;
    int cOwn = g / ACC;
    int rank = g - cOwn * ACC;

    int d = 1;
    for (; d + 3 < NCLS; d += 4) {
        int ca = cOwn + d;     if (ca >= NCLS) ca -= NCLS;
        int cb = cOwn + d + 1; if (cb >= NCLS) cb -= NCLS;
        int cc = cOwn + d + 2; if (cc >= NCLS) cc -= NCLS;
        int cd = cOwn + d + 3; if (cd >= NCLS) cd -= NCLS;
        const u64* LA = L + ca * ACC;
        const u64* LB = L + cb * ACC;
        const u64* LC = L + cc * ACC;
        const u64* LD = L + cd * ACC;
        int na = 0, nb = 0, nc = 0, nd = 0;
#pragma unroll
        for (int s2 = 32; s2; s2 >>= 1) {
            int ta = na + s2, tb2 = nb + s2, tc = nc + s2, td = nd + s2;
            if (ta <= ACC && LA[ta - 1] > key) na = ta;
            if (tb2 <= ACC && LB[tb2 - 1] > key) nb = tb2;
            if (tc <= ACC && LC[tc - 1] > key) nc = tc;
            if (td <= ACC && LD[td - 1] > key) nd = td;
        }
        rank += na + nb + nc + nd;
        if (rank >= MAXDET) return;
    }
    for (; d < NCLS; d++) {
        int c2 = cOwn + d; if (c2 >= NCLS) c2 -= NCLS;
        const u64* Lc = L + c2 * ACC;
        int cn = 0;
#pragma unroll
        for (int s2 = 32; s2; s2 >>= 1) {
            int ncx = cn + s2;
            if (ncx <= ACC && Lc[ncx - 1] > key) cn = ncx;
        }
        rank += cn;
        if (rank >= MAXDET) return;
    }

    int cc  = (int)(key & 127);
    int idx = 32767 - (int)((key >> 7) & 32767);
    float conf = __uint_as_float((unsigned)(key >> 22));
    const float* q = p + ((long)b * NBOX + idx) * CH;
    float x = q[0], y = q[1], w = q[2], h = q[3];
    float hw = w * 0.5f, hh = h * 0.5f;
    float* row = outRows + ((long)b * MAXDET + rank) * 6;
    row[0] = x - hw; row[1] = y - hh; row[2] = x + hw; row[3] = y + hh;
    row[4] = conf;   row[5] = (float)cc;
    outKeep[b * MAXDET + rank] = 1.0f;
}

extern "C" void kernel_launch(void* const* d_in, const int* in_sizes, int n_in,
                              void* d_out, int out_size, void* d_ws, size_t ws_size,
                              hipStream_t stream) {
    const float* p = (const float*)d_in[0];
    float* out = (float*)d_out;

    char* ws = (char*)d_ws;
    int* cnt = (int*)ws;                                    // 81,920 B padded counters
    u64* rec = (u64*)(ws + BATCH * NCLS * CNTPAD * 4);      // 16*80*512*32 B = 20.97 MB
    u64* accKey = (u64*)(ws + BATCH * NCLS * CNTPAD * 4
                            + (size_t)BATCH * NCLS * CAP * 32);  // 327,680 B

    hipMemsetAsync(cnt, 0, BATCH * NCLS * CNTPAD * sizeof(int), stream);
    pre_kernel<<<(BATCH * NBOX) / RPB, 256, 0, stream>>>(p, cnt, rec, out, out_size);
    nms_kernel<<<BATCH * NCLS, 64, 0, stream>>>(cnt, rec, accKey);
    dim3 gM(NCLS * ACC / 256, BATCH);
    merge_kernel<<<gM, 256, 0, stream>>>(p, accKey, out, out + (size_t)BATCH * MAXDET * 6);
}

// Round 10
// 257.040 us; speedup vs baseline: 1.0910x; 1.0225x over previous
//
#include <hip/hip_runtime.h>
#include <cstdint>
#include <cfloat>

#define BATCH 16
#define NBOX 25200
#define CH 85
#define NCLS 80
#define CAP 512
#define SEGCAP 128   // CAP/4, per-sub-counter capacity
#define ACC 32       // max picks per (image,class); P(needed>32) ~ 1e-17
#define MAXDET 300
#define RPB 56       // rows per block: 19,040 B LDS -> 8 blocks/CU (was 112 @ 4)
#define CNTPAD 16    // ints per counter slot (64B line); segs 0..3 share one line

typedef unsigned long long u64;

// ---------------- kernel A: staged per-row conf/argmax + bucket by (image,class)
// Writes a packed 32B record per candidate: [float4 offset-box][u64 key][8B pad]
// (logic unchanged from R6/R9-verified; RPB 112->56 for 2x occupancy)
__global__ __launch_bounds__(256) void pre_kernel(const float* __restrict__ p,
                                                  int* __restrict__ cnt,
                                                  u64* __restrict__ rec,
                                                  float* __restrict__ outZero,
                                                  int outN) {
#pragma clang fp contract(off)
    __shared__ float s[RPB * CH];          // 19,040 B
    int tid = threadIdx.x;

    long z = (long)blockIdx.x * 256 + tid;
    if (z < outN) outZero[z] = 0.0f;

    long blockRow = (long)blockIdx.x * RPB;

    const float4* p4 = (const float4*)(p + blockRow * CH);
    float4* s4 = (float4*)s;
    for (int t = tid; t < RPB * CH / 4; t += 256) {
        __builtin_amdgcn_global_load_lds(
            (const __attribute__((address_space(1))) void*)(p4 + t),
            (__attribute__((address_space(3))) void*)(s4 + (t & ~63)),
            16, 0, 0);
    }
    __syncthreads();

    int r = tid >> 1;
    int half = tid & 1;
    if (r < RPB) {
        const float* row = s + r * CH;
        float obj = row[4];

        float v = -FLT_MAX; int c = 1000;
        int c0 = half * 40;
        for (int k = 0; k < 40; k++) {
            float sc = row[5 + c0 + k] * obj;  // multiply-first, matches reference
            int cc = c0 + k;
            if (sc > v) { v = sc; c = cc; }    // strict > keeps first max
        }
        float v2 = __shfl_xor(v, 1);
        int   cz = __shfl_xor(c, 1);
        if (v2 > v || (v2 == v && cz < c)) { v = v2; c = cz; }

        if (half == 0 && obj > 0.25f && v > 0.25f) {
            int wid = (int)blockRow + r;
            int b   = wid / NBOX;
            int idx = wid - b * NBOX;
            u64 key = ((u64)__float_as_uint(v) << 22) | ((u64)(32767 - idx) << 7) | (u64)c;
            int bkt = b * NCLS + c;
            int seg = idx & 3;
            int pos = atomicAdd(&cnt[bkt * CNTPAD + seg], 1);
            if (pos < SEGCAP) {
                float x = row[0], y = row[1], w = row[2], h = row[3];
                float hw = w * 0.5f, hh = h * 0.5f;
                float offc = (float)c * 4096.0f;
                float4 b4;
                b4.x = (x - hw) + offc; b4.y = (y - hh) + offc;
                b4.z = (x + hw) + offc; b4.w = (y + hh) + offc;
                u64* slot = rec + ((long)bkt * CAP + seg * SEGCAP + pos) * 4;
                *(float4*)slot = b4;
                slot[2] = key;
            }
        }
    }
}

// ---------------- kernel B: 4-wave LDS-bitonic sort + row-matrix greedy --------
// TLP fix: 256 threads (4 waves) per bucket -> 20 waves/CU (was 5). Sort is a
// textbook 512-element LDS bitonic (45 stages, thread i = 2t-(t&(J-1)) handles
// pair (i, i+J); desc when (i&K)==0). Tagged keys (key<<9|slot) give a total
// order (R9-verified comparator). Untag + rank rewrite, then R9's verified
// tile/kill-row/scalar-resolve executed by wave 0; nacc shared via LDS so all
// barriers are block-uniform.
__global__ __launch_bounds__(256) void nms_kernel(const int* __restrict__ cnt,
                                                  const u64* __restrict__ rec,
                                                  u64* __restrict__ accKey) {
#pragma clang fp contract(off)
    __shared__ float4 boxSlot[CAP];        // 8,192 B: slot-indexed boxes
    __shared__ u64    keyArr[CAP];         // 4,096 B: tagged keys -> sorted -> untagged
    __shared__ float4 boxRank[CAP];        // 8,192 B: rank-indexed boxes
    __shared__ u64    rowLds[64];          //   512 B
    __shared__ int    pickPosLds[ACC];     //   128 B
    __shared__ int    naccLds;
    int tid = threadIdx.x;
    int bkt = blockIdx.x;

    const int* cb = cnt + bkt * CNTPAD;
    int ns0 = cb[0], ns1 = cb[1], ns2 = cb[2], ns3 = cb[3];
    ns0 = ns0 < SEGCAP ? ns0 : SEGCAP;
    ns1 = ns1 < SEGCAP ? ns1 : SEGCAP;
    ns2 = ns2 < SEGCAP ? ns2 : SEGCAP;
    ns3 = ns3 < SEGCAP ? ns3 : SEGCAP;
    int nsg[4] = {ns0, ns1, ns2, ns3};
    int ntot = ns0 + ns1 + ns2 + ns3;

    // 1) cooperative load: slot s = seg*128 + off; tag = slot (9 bits)
    const u64* R = rec + (long)bkt * CAP * 4;
    for (int s = tid; s < CAP; s += 256) {
        float4 b4 = *(const float4*)(R + (long)s * 4);
        u64 k = R[(long)s * 4 + 2];
        boxSlot[s] = b4;
        int seg = s >> 7, off = s & 127;
        keyArr[s] = (off < nsg[seg]) ? ((k << 9) | (u64)s) : 0ULL;
    }
    __syncthreads();

    // 2) LDS bitonic sort, descending (45 stages)
    for (int K = 2; K <= CAP; K <<= 1) {
        for (int J = K >> 1; J >= 1; J >>= 1) {
            int i = (tid << 1) - (tid & (J - 1));
            bool desc = ((i & K) == 0);
            u64 a = keyArr[i], b = keyArr[i + J];
            bool sw = desc ? (a < b) : (a > b);
            if (sw) { keyArr[i] = b; keyArr[i + J] = a; }
            __syncthreads();
        }
    }

    // 3) untag + rank rewrite: boxRank[rank] = boxSlot[tag]; keyArr[rank] >>= 9
    for (int s = tid; s < CAP; s += 256) {
        u64 tk = keyArr[s];
        boxRank[s] = boxSlot[(int)(tk & 511u)];
        keyArr[s] = tk >> 9;               // untagged key (0 for dead)
    }
    if (tid == 0) naccLds = 0;
    __syncthreads();

    // 4) tile loop (R9-verified logic; wave 0 computes, barriers block-uniform)
    long obase = (long)bkt * ACC;
    for (int tb = 0; tb < CAP; tb += 64) {
        int nacc0 = naccLds;               // uniform (barrier-protected)
        if (tb >= ntot || nacc0 >= ACC) break;   // uniform break

        bool dead = true;
        float4 my = make_float4(0.f, 0.f, 0.f, 0.f);
        if (tid < 64) {
            bool valid = (tb + tid) < ntot;
            my = boxRank[tb + tid];
            float myA = (my.z - my.x) * (my.w - my.y);
            dead = !valid;

            // cross-suppression by picks from earlier tiles (rarely reached)
            if (tb > 0) {
                for (int k = 0; k < nacc0; k++) {
                    float4 B = boxRank[pickPosLds[k]];   // uniform, pipelined
                    float xx1 = fmaxf(B.x, my.x);
                    float yy1 = fmaxf(B.y, my.y);
                    float xx2 = fminf(B.z, my.z);
                    float yy2 = fminf(B.w, my.w);
                    float inter = fmaxf(xx2 - xx1, 0.0f) * fmaxf(yy2 - yy1, 0.0f);
                    float A = (B.z - B.x) * (B.w - B.y);
                    float uni = (A + myA) - inter;
                    if (valid && (inter / uni > 0.45f)) dead = true;
                }
            }

            // kill-row: bit j = "I suppress rank tb+j"; 63 independent reads
            u64 row = 0;
#pragma unroll 4
            for (int k = 1; k < 64; k++) {
                int j = (tid + k) & 63;
                float4 B = boxRank[tb + j];
                float xx1 = fmaxf(my.x, B.x);
                float yy1 = fmaxf(my.y, B.y);
                float xx2 = fminf(my.z, B.z);
                float yy2 = fminf(my.w, B.w);
                float inter = fmaxf(xx2 - xx1, 0.0f) * fmaxf(yy2 - yy1, 0.0f);
                float aj = (B.z - B.x) * (B.w - B.y);
                float uni = (myA + aj) - inter;
                if (inter / uni > 0.45f) row |= 1ULL << j;
            }
            rowLds[tid] = row;
        }
        __syncthreads();                   // rows visible; waves aligned

        if (tid < 64) {
            u64 alive = __ballot(!dead);   // wave 0 only
            int nacc = nacc0;
            while (alive != 0ULL && nacc < ACC) {
                int pos = (int)__ffsll((long long)alive) - 1;  // lowest rank alive
                if (tid == 0) {
                    accKey[obase + nacc] = keyArr[tb + pos];
                    pickPosLds[nacc] = tb + pos;
                }
                nacc++;
                u64 krow = rowLds[pos];    // uniform broadcast ds_read_b64
                alive &= ~krow;
                alive &= ~(1ULL << pos);
            }
            if (tid == 0) naccLds = nacc;
        }
        __syncthreads();                   // naccLds visible for next tile
    }

    __syncthreads();
    int fn = naccLds;
    for (int t2 = fn + tid; t2 < ACC; t2 += 256) accKey[obase + t2] = 0ULL;
}

// ---------------- kernel C: rank-based merge (unchanged, verified) -------------
__global__ __launch_bounds__(256) void merge_kernel(const float* __restrict__ p,
                                                    const u64* __restrict__ accKey,
                                                    float* __restrict__ outRows,
                                                    float* __restrict__ outKeep) {
#pragma clang fp contract(off)
    __shared__ u64 L[NCLS * ACC];          // 20,480 B
    int tid = threadIdx.x;
    int b = blockIdx.y;
    const u64* src = accKey + (long)b * NCLS * ACC;
    for (int t = tid; t < NCLS * ACC; t += 256) L[t] = src[t];
    __syncthreads();

    int g = blockIdx.x * 256 + tid;
    u64 key = L[g];
    if (key == 0ULL) return;
    int cOwn = g / ACC;
    int rank = g - cOwn * ACC;

    int d = 1;
    for (; d + 3 < NCLS; d += 4) {
        int ca = cOwn + d;     if (ca >= NCLS) ca -= NCLS;
        int cb = cOwn + d + 1; if (cb >= NCLS) cb -= NCLS;
        int cc = cOwn + d + 2; if (cc >= NCLS) cc -= NCLS;
        int cd = cOwn + d + 3; if (cd >= NCLS) cd -= NCLS;
        const u64* LA = L + ca * ACC;
        const u64* LB = L + cb * ACC;
        const u64* LC = L + cc * ACC;
        const u64* LD = L + cd * ACC;
        int na = 0, nb = 0, nc = 0, nd = 0;
#pragma unroll
        for (int s2 = 32; s2; s2 >>= 1) {
            int ta = na + s2, tb2 = nb + s2, tc = nc + s2, td = nd + s2;
            if (ta <= ACC && LA[ta - 1] > key) na = ta;
            if (tb2 <= ACC && LB[tb2 - 1] > key) nb = tb2;
            if (tc <= ACC && LC[tc - 1] > key) nc = tc;
            if (td <= ACC && LD[td - 1] > key) nd = td;
        }
        rank += na + nb + nc + nd;
        if (rank >= MAXDET) return;
    }
    for (; d < NCLS; d++) {
        int c2 = cOwn + d; if (c2 >= NCLS) c2 -= NCLS;
        const u64* Lc = L + c2 * ACC;
        int cn = 0;
#pragma unroll
        for (int s2 = 32; s2; s2 >>= 1) {
            int ncx = cn + s2;
            if (ncx <= ACC && Lc[ncx - 1] > key) cn = ncx;
        }
        rank += cn;
        if (rank >= MAXDET) return;
    }

    int cc  = (int)(key & 127);
    int idx = 32767 - (int)((key >> 7) & 32767);
    float conf = __uint_as_float((unsigned)(key >> 22));
    const float* q = p + ((long)b * NBOX + idx) * CH;
    float x = q[0], y = q[1], w = q[2], h = q[3];
    float hw = w * 0.5f, hh = h * 0.5f;
    float* row = outRows + ((long)b * MAXDET + rank) * 6;
    row[0] = x - hw; row[1] = y - hh; row[2] = x + hw; row[3] = y + hh;
    row[4] = conf;   row[5] = (float)cc;
    outKeep[b * MAXDET + rank] = 1.0f;
}

extern "C" void kernel_launch(void* const* d_in, const int* in_sizes, int n_in,
                              void* d_out, int out_size, void* d_ws, size_t ws_size,
                              hipStream_t stream) {
    const float* p = (const float*)d_in[0];
    float* out = (float*)d_out;

    char* ws = (char*)d_ws;
    int* cnt = (int*)ws;                                    // 81,920 B padded counters
    u64* rec = (u64*)(ws + BATCH * NCLS * CNTPAD * 4);      // 16*80*512*32 B = 20.97 MB
    u64* accKey = (u64*)(ws + BATCH * NCLS * CNTPAD * 4
                            + (size_t)BATCH * NCLS * CAP * 32);  // 327,680 B

    hipMemsetAsync(cnt, 0, BATCH * NCLS * CNTPAD * sizeof(int), stream);
    pre_kernel<<<(BATCH * NBOX) / RPB, 256, 0, stream>>>(p, cnt, rec, out, out_size);
    nms_kernel<<<BATCH * NCLS, 256, 0, stream>>>(cnt, rec, accKey);
    dim3 gM(NCLS * ACC / 256, BATCH);
    merge_kernel<<<gM, 256, 0, stream>>>(p, accKey, out, out + (size_t)BATCH * MAXDET * 6);
}